// Round 21
// baseline (424.175 us; speedup 1.0000x reference)
//
#include <hip/hip_runtime.h>

typedef __attribute__((ext_vector_type(4))) float f32x4;
typedef __attribute__((ext_vector_type(8))) _Float16 f16x8;
typedef __attribute__((ext_vector_type(4))) unsigned short u16x4;
typedef __attribute__((ext_vector_type(8))) unsigned short u16x8;

#define NB 4096
#define NS 6
#define NC 2048
#define MTOT (NB * NS)   // 24576

static __device__ __forceinline__ unsigned short f2h_bits(float f) {
  _Float16 h = (_Float16)f;
  unsigned short b;
  __builtin_memcpy(&b, &h, 2);
  return b;
}
static __device__ __forceinline__ float h2f(unsigned short b) {
  _Float16 h;
  __builtin_memcpy(&h, &b, 2);
  return (float)h;
}

// ---------------- fused prep: x->fp16, [Wq;Wk]->fp16, Wv->fp16 ----------------
#define NX4 12582912   // MTOT*NC/4
#define NW4 262144     // 512*2048/4
#define NV4 1048576    // 2048*2048/4
__global__ void prep_all(const float* __restrict__ x, const float* __restrict__ Wq,
                         const float* __restrict__ Wk, const float* __restrict__ Wv,
                         unsigned short* __restrict__ xh, unsigned short* __restrict__ wqk,
                         unsigned short* __restrict__ wvh) {
  long i = blockIdx.x * blockDim.x + threadIdx.x;
  const long stride = (long)gridDim.x * blockDim.x;
  for (; i < NX4 + NW4 + NV4; i += stride) {
    f32x4 v;
    unsigned short* dst;
    long di;
    if (i < NX4) {
      v = reinterpret_cast<const f32x4*>(x)[i];
      dst = xh; di = i;
    } else if (i < NX4 + NW4) {
      const long j = i - NX4;
      const int row = (int)(j >> 9);
      const int col4 = (int)(j & 511);
      const float* src = (row < 256) ? (Wq + (size_t)row * NC)
                                     : (Wk + (size_t)(row - 256) * NC);
      v = reinterpret_cast<const f32x4*>(src)[col4];
      dst = wqk; di = j;
    } else {
      const long j = i - NX4 - NW4;
      v = reinterpret_cast<const f32x4*>(Wv)[j];
      dst = wvh; di = j;
    }
    u16x4 o;
#pragma unroll
    for (int j = 0; j < 4; ++j) o[j] = f2h_bits(v[j]);
    reinterpret_cast<u16x4*>(dst)[di] = o;
  }
}

// -------- 256x256 GEMM, BK=64, m201-EXACT phase pattern (round 21) --------
// C[M,N] = A[M,2048] * B[N,2048]^T ; A/B fp16, C fp32.
// LDS 128KB = 2 buf x {A0,A1,B0,B1} half-regions of 16KB (128 rows x 64 k).
// Subtile = 1KB = [16 rows][32 k] fp16, XOR swizzle both sides.
// Per tile tau: 4 phases, each the FULL m201 pattern:
//   {ds_reads ; stage 1 half ; s_barrier ; lgkmcnt(0)+sched_barrier ;
//    setprio(1) ; 16 MFMA ; setprio(0) ; s_barrier}
// Quadrants (0,0),(0,1),(1,1),(1,0); stage schedule P0->(t+1).A0,
// P1->(t+1).A1, P2->(t+2).B0, P3->(t+2).B1; vmcnt(4) once per tile at P3
// (drains exactly tile t+1's 4 halves; keeps (t+2).B0,B1); WRAPT exact tail.
// Ledger identical to r18 (passed); added barriers only strengthen ordering.

#define FENCE() asm volatile("" ::: "memory")
#define BAR() do { FENCE(); __builtin_amdgcn_s_barrier(); FENCE(); } while (0)
#define VM4BAR() do { FENCE(); asm volatile("s_waitcnt vmcnt(4)" ::: "memory"); \
                      __builtin_amdgcn_s_barrier(); FENCE(); } while (0)
#define LGKM0() do { asm volatile("s_waitcnt lgkmcnt(0)" ::: "memory"); \
                     __builtin_amdgcn_sched_barrier(0); } while (0)

__device__ __forceinline__ void stage_half(const unsigned short* g, int row0, int k0,
                                           char* region, int wid, int lane) {
  const int sl = lane ^ ((lane >> 4) & 1) ^ (((lane >> 5) & 1) << 1);
#pragma unroll
  for (int i = 0; i < 2; ++i) {
    const int c = wid * 2 + i;          // 16 subtiles = 128 rows x 64 k
    const unsigned short* src =
        g + (size_t)(row0 + (c >> 1) * 16 + (sl >> 2)) * 2048 +
        (unsigned)(k0 + (c & 1) * 32 + (sl & 3) * 8);
    __builtin_amdgcn_global_load_lds(
        (__attribute__((address_space(1))) void*)src,
        (__attribute__((address_space(3))) void*)(region + c * 1024), 16, 0, 0);
  }
}

template <int N, bool EPI, bool NFAST>
__global__ void __launch_bounds__(512, 2)
gemm256(const unsigned short* __restrict__ A, const unsigned short* __restrict__ B,
        float* __restrict__ C, const unsigned short* __restrict__ resid,
        const float* __restrict__ gam) {
  constexpr int NT = 2048 / 64;         // 32 K-tiles
  constexpr int MT = MTOT / 256;        // 96
  constexpr int NXT = N / 256;
  constexpr int NWG = MT * NXT;         // %8==0 at both call sites
  constexpr int CPX = NWG / 8;
  __shared__ char lds[131072];

  const int bid = blockIdx.x;
  const int wg = (bid & 7) * CPX + (bid >> 3);   // XCD swizzle
  const int bx = NFAST ? (wg % NXT) : (wg / MT);
  const int by = NFAST ? (wg / NXT) : (wg % MT);
  const int m0 = by * 256, n0 = bx * 256;

  const int t = threadIdx.x;
  const int lane = t & 63;
  const int wid = t >> 6;
  const int wr = wid >> 2, wc = wid & 3;     // wave owns C rows wr*128, cols wc*64
  const int laneOff = (lane & 15) * 64 + (lane >> 4) * 16;
  const int swzOff = laneOff ^ (((laneOff >> 9) & 1) << 5) ^ (((laneOff >> 8) & 1) << 4);

  f32x4 acc[8][4] = {};
  f16x8 Aq[4][2], B0q[2][2], B1q[2][2];

#define WRAPT(TT) ((TT) >= NT ? (TT) - NT : (TT))
#define LDA(MH) do { _Pragma("unroll") for (int fm = 0; fm < 4; ++fm) \
    _Pragma("unroll") for (int kk = 0; kk < 2; ++kk) \
      Aq[fm][kk] = *reinterpret_cast<const f16x8*>( \
          bufc + wr * 16384 + ((((MH) * 4 + fm) * 2 + kk)) * 1024 + swzOff); } while (0)
#define LDB(NH, BQ) do { _Pragma("unroll") for (int fn = 0; fn < 2; ++fn) \
    _Pragma("unroll") for (int kk = 0; kk < 2; ++kk) \
      BQ[fn][kk] = *reinterpret_cast<const f16x8*>( \
          bufc + 32768 + (wc >> 1) * 16384 + \
          ((((wc & 1) * 4 + (NH) * 2 + fn) * 2 + kk)) * 1024 + swzOff); } while (0)
#define MFQ(MH, NH, BQ) do { __builtin_amdgcn_s_setprio(1); \
    _Pragma("unroll") for (int fm = 0; fm < 4; ++fm) \
      _Pragma("unroll") for (int fn = 0; fn < 2; ++fn) \
        _Pragma("unroll") for (int kk = 0; kk < 2; ++kk) \
          acc[(MH) * 4 + fm][(NH) * 2 + fn] = __builtin_amdgcn_mfma_f32_16x16x32_f16( \
              Aq[fm][kk], BQ[fn][kk], acc[(MH) * 4 + fm][(NH) * 2 + fn], 0, 0, 0); \
    __builtin_amdgcn_s_setprio(0); } while (0)

  // prologue: T0 complete + T1.B0,B1; vmcnt(4) drains T0, keeps T1.B halves
  stage_half(A, m0,       0,  lds,         wid, lane);   // T0.A0
  stage_half(A, m0 + 128, 0,  lds + 16384, wid, lane);   // T0.A1
  stage_half(B, n0,       0,  lds + 32768, wid, lane);   // T0.B0
  stage_half(B, n0 + 128, 0,  lds + 49152, wid, lane);   // T0.B1
  stage_half(B, n0,       64, lds + 65536 + 32768, wid, lane);  // T1.B0
  stage_half(B, n0 + 128, 64, lds + 65536 + 49152, wid, lane);  // T1.B1
  VM4BAR();

  for (int tau = 0; tau < NT; ++tau) {
    char* bufc = lds + (tau & 1) * 65536;
    char* bufo = lds + ((tau & 1) ^ 1) * 65536;
    // P0: quadrant (0,0); stage (tau+1).A0
    LDA(0);
    LDB(0, B0q);
    stage_half(A, m0, WRAPT(tau + 1) * 64, bufo, wid, lane);
    BAR();
    LGKM0();
    MFQ(0, 0, B0q);
    BAR();
    // P1: quadrant (0,1); stage (tau+1).A1
    LDB(1, B1q);
    stage_half(A, m0 + 128, WRAPT(tau + 1) * 64, bufo + 16384, wid, lane);
    BAR();
    LGKM0();
    MFQ(0, 1, B1q);
    BAR();
    // P2: quadrant (1,1); stage (tau+2).B0 (bufc B-region; reads consumed P0/P1)
    LDA(1);
    stage_half(B, n0, WRAPT(tau + 2) * 64, bufc + 32768, wid, lane);
    BAR();
    LGKM0();
    MFQ(1, 1, B1q);
    BAR();
    // P3: quadrant (1,0) (all regs); stage (tau+2).B1; counted drain
    stage_half(B, n0 + 128, WRAPT(tau + 2) * 64, bufc + 49152, wid, lane);
    VM4BAR();    // 12 -> 4: drains tile tau+1 fully; keeps (tau+2).B0,B1
    MFQ(1, 0, B0q);
    BAR();
  }

#undef MFQ
#undef LDB
#undef LDA
#undef WRAPT

  // epilogue: C/D layout col = lane&15, row = (lane>>4)*4 + j ; resid fp16
  const float g = EPI ? gam[0] : 0.f;
#pragma unroll
  for (int m = 0; m < 8; ++m)
#pragma unroll
    for (int n = 0; n < 4; ++n)
#pragma unroll
      for (int j = 0; j < 4; ++j) {
        const int r = m0 + wr * 128 + m * 16 + (lane >> 4) * 4 + j;
        const int c = n0 + wc * 64 + n * 16 + (lane & 15);
        const size_t idx = (size_t)r * (size_t)N + (size_t)c;
        float v = acc[m][n][j];
        if (EPI) v = g * v + h2f(resid[idx]);
        C[idx] = v;
      }
}

// ---------------- per-batch: energy -> softmax -> attn out + y = attn@x ----------------
__global__ void __launch_bounds__(256)
attn_fuse(const float* __restrict__ QK,          // [MTOT, 512] cols 0..255=q, 256..511=k
          const unsigned short* __restrict__ xh, // [MTOT, 2048] fp16
          float* __restrict__ attn_out,          // [NB, 36]
          unsigned short* __restrict__ y)        // [MTOT, 2048] fp16
{
  __shared__ float qk[NS * 512];
  __shared__ float eng[36];
  __shared__ float att[36];
  const int b = blockIdx.x;
  const int t = threadIdx.x;
  {
    const f32x4* src = reinterpret_cast<const f32x4*>(QK + (size_t)b * (NS * 512));
    f32x4* dst = reinterpret_cast<f32x4*>(qk);
    for (int i = t; i < (NS * 512) / 4; i += 256) dst[i] = src[i];
  }
  __syncthreads();
  if (t < 144) {
    const int s = t / 24;
    const int rem = t - s * 24;
    const int u = rem >> 2;
    const int sub = rem & 3;
    const float* qr = qk + s * 512;
    const float* kr = qk + u * 512 + 256;
    float sum = 0.f;
    const int d0 = sub * 64;
#pragma unroll 4
    for (int d = 0; d < 64; ++d) sum += qr[d0 + d] * kr[d0 + d];
    sum += __shfl_xor(sum, 1);
    sum += __shfl_xor(sum, 2);
    if (sub == 0) eng[s * 6 + u] = sum;
  }
  __syncthreads();
  if (t < 6) {
    float e[6];
#pragma unroll
    for (int u = 0; u < 6; ++u) e[u] = eng[t * 6 + u];
    float mx = e[0];
#pragma unroll
    for (int u = 1; u < 6; ++u) mx = fmaxf(mx, e[u]);
    float p[6];
    float sm = 0.f;
#pragma unroll
    for (int u = 0; u < 6; ++u) { p[u] = expf(e[u] - mx); sm += p[u]; }
    const float inv = 1.0f / sm;
#pragma unroll
    for (int u = 0; u < 6; ++u) {
      const float a = p[u] * inv;
      att[t * 6 + u] = a;
      attn_out[(size_t)b * 36 + t * 6 + u] = a;
    }
  }
  __syncthreads();
  const unsigned short* xb = xh + (size_t)b * (NS * NC);
  unsigned short* yb = y + (size_t)b * (NS * NC);
  const int c0 = t * 8;
  f32x4 xv[12];
#pragma unroll
  for (int u = 0; u < 6; ++u) {
    u16x8 v = *reinterpret_cast<const u16x8*>(xb + u * NC + c0);
#pragma unroll
    for (int j = 0; j < 4; ++j) {
      xv[2 * u][j] = h2f(v[j]);
      xv[2 * u + 1][j] = h2f(v[4 + j]);
    }
  }
#pragma unroll
  for (int s = 0; s < 6; ++s) {
    f32x4 a0 = 0.f, a1 = 0.f;
#pragma unroll
    for (int u = 0; u < 6; ++u) {
      const float w = att[s * 6 + u];
      a0 += w * xv[2 * u];
      a1 += w * xv[2 * u + 1];
    }
    u16x8 o;
#pragma unroll
    for (int j = 0; j < 4; ++j) { o[j] = f2h_bits(a0[j]); o[4 + j] = f2h_bits(a1[j]); }
    *reinterpret_cast<u16x8*>(yb + s * NC + c0) = o;
  }
}

extern "C" void kernel_launch(void* const* d_in, const int* in_sizes, int n_in,
                              void* d_out, int out_size, void* d_ws, size_t ws_size,
                              hipStream_t stream) {
  (void)in_sizes; (void)n_in; (void)out_size; (void)ws_size;
  const float* x   = (const float*)d_in[0];
  const float* Wq  = (const float*)d_in[1];
  const float* Wk  = (const float*)d_in[2];
  const float* Wv  = (const float*)d_in[3];
  const float* gam = (const float*)d_in[4];
  float* out = (float*)d_out;
  float* attn_out = out + (size_t)MTOT * NC;

  char* ws = (char*)d_ws;
  unsigned short* xh  = (unsigned short*)(ws);                    // 100663296 B
  unsigned short* yb  = (unsigned short*)(ws + 100663296ull);     // 100663296 B (y)
  unsigned short* wqk = (unsigned short*)(ws + 201326592ull);     // 2097152 B
  unsigned short* wvh = (unsigned short*)(ws + 203423744ull);     // 8388608 B
  float*          qkb = (float*)(ws + 211812352ull);              // 50331648 B

  prep_all<<<2048, 256, 0, stream>>>(x, Wq, Wk, Wv, xh, wqk, wvh);

  // QK = x @ [Wq;Wk]^T, single-pass fp16
  gemm256<512, false, false><<<192, 512, 0, stream>>>(
      xh, wqk, qkb, nullptr, nullptr);

  // energies + softmax + attention output + y = attn @ x
  attn_fuse<<<NB, 256, 0, stream>>>(qkb, xh, attn_out, yb);

  // out = gamma * (y @ Wv^T) + x_fp16    (n-fast block order for y L2 reuse)
  gemm256<2048, true, true><<<768, 512, 0, stream>>>(
      yb, wvh, out, xh, gam);
}

// Round 22
// 400.883 us; speedup vs baseline: 1.0581x; 1.0581x over previous
//
#include <hip/hip_runtime.h>

typedef __attribute__((ext_vector_type(4))) float f32x4;
typedef __attribute__((ext_vector_type(8))) _Float16 f16x8;
typedef __attribute__((ext_vector_type(4))) unsigned short u16x4;
typedef __attribute__((ext_vector_type(8))) unsigned short u16x8;

#define NB 4096
#define NS 6
#define NC 2048
#define MTOT (NB * NS)   // 24576

static __device__ __forceinline__ unsigned short f2h_bits(float f) {
  _Float16 h = (_Float16)f;
  unsigned short b;
  __builtin_memcpy(&b, &h, 2);
  return b;
}
static __device__ __forceinline__ float h2f(unsigned short b) {
  _Float16 h;
  __builtin_memcpy(&h, &b, 2);
  return (float)h;
}

// ---------------- fused prep: x->fp16, [Wq;Wk]->fp16, Wv->fp16 ----------------
#define NX4 12582912   // MTOT*NC/4
#define NW4 262144     // 512*2048/4
#define NV4 1048576    // 2048*2048/4
__global__ void prep_all(const float* __restrict__ x, const float* __restrict__ Wq,
                         const float* __restrict__ Wk, const float* __restrict__ Wv,
                         unsigned short* __restrict__ xh, unsigned short* __restrict__ wqk,
                         unsigned short* __restrict__ wvh) {
  long i = blockIdx.x * blockDim.x + threadIdx.x;
  const long stride = (long)gridDim.x * blockDim.x;
  for (; i < NX4 + NW4 + NV4; i += stride) {
    f32x4 v;
    unsigned short* dst;
    long di;
    if (i < NX4) {
      v = reinterpret_cast<const f32x4*>(x)[i];
      dst = xh; di = i;
    } else if (i < NX4 + NW4) {
      const long j = i - NX4;
      const int row = (int)(j >> 9);
      const int col4 = (int)(j & 511);
      const float* src = (row < 256) ? (Wq + (size_t)row * NC)
                                     : (Wk + (size_t)(row - 256) * NC);
      v = reinterpret_cast<const f32x4*>(src)[col4];
      dst = wqk; di = j;
    } else {
      const long j = i - NX4 - NW4;
      v = reinterpret_cast<const f32x4*>(Wv)[j];
      dst = wvh; di = j;
    }
    u16x4 o;
#pragma unroll
    for (int j = 0; j < 4; ++j) o[j] = f2h_bits(v[j]);
    reinterpret_cast<u16x4*>(dst)[di] = o;
  }
}

// -------- 256x256 GEMM, BK=64, 4-phase/tile, 2 sync points/tile --------
// C[M,N] = A[M,2048] * B[N,2048]^T ; A/B fp16, C fp32.
// BEST-MEASURED CONFIG (r20: total 401.7us, G2 232us @ 888 TF, MfmaUtil 40%).
// Barrier-density curve sampled {2,4,4+lgkm,8,9}/tile -> {40,39.2,39.1,33.7,
// 34.6}% MfmaUtil: this 2-sync variant is the optimum of the family.
// LDS 128KB = 2 buf x {A0,A1,B0,B1} half-regions of 16KB (128 rows x 64 k).
// Subtile = 1KB = [16 rows][32 k] fp16, XOR swizzle both sides.
// Per tile tau: quadrants (0,0),(0,1),(1,1),(1,0); stage schedule P0->(t+1).A0,
// P1->(t+1).A1, P2->(t+2).B0, P3->(t+2).B1; vmcnt(4) once per tile drains
// exactly tile t+1 (keeps (t+2).B0,B1); WRAPT exact tail.
//  - BAR at P1-end: all waves issued their B0/B1 reads (P0/P1) before the
//    P2/P3 restage of bufc's B regions can land (stage flight ~300cyc).
//  - VM4BAR at P3: ledger drain + cross-wave visibility of tile t+1.
//  A0/A1 stages (bufo) have readers one tile old, separated by the previous
//  tile's VM4BAR. Max wave skew < 1 tile. Between sync points waves free-run.

#define FENCE() asm volatile("" ::: "memory")
#define BAR() do { FENCE(); __builtin_amdgcn_s_barrier(); FENCE(); } while (0)
#define VM4BAR() do { FENCE(); asm volatile("s_waitcnt vmcnt(4)" ::: "memory"); \
                      __builtin_amdgcn_s_barrier(); FENCE(); } while (0)

__device__ __forceinline__ void stage_half(const unsigned short* g, int row0, int k0,
                                           char* region, int wid, int lane) {
  const int sl = lane ^ ((lane >> 4) & 1) ^ (((lane >> 5) & 1) << 1);
#pragma unroll
  for (int i = 0; i < 2; ++i) {
    const int c = wid * 2 + i;          // 16 subtiles = 128 rows x 64 k
    const unsigned short* src =
        g + (size_t)(row0 + (c >> 1) * 16 + (sl >> 2)) * 2048 +
        (unsigned)(k0 + (c & 1) * 32 + (sl & 3) * 8);
    __builtin_amdgcn_global_load_lds(
        (__attribute__((address_space(1))) void*)src,
        (__attribute__((address_space(3))) void*)(region + c * 1024), 16, 0, 0);
  }
}

template <int N, bool EPI, bool NFAST>
__global__ void __launch_bounds__(512, 2)
gemm256(const unsigned short* __restrict__ A, const unsigned short* __restrict__ B,
        float* __restrict__ C, const unsigned short* __restrict__ resid,
        const float* __restrict__ gam) {
  constexpr int NT = 2048 / 64;         // 32 K-tiles
  constexpr int MT = MTOT / 256;        // 96
  constexpr int NXT = N / 256;
  constexpr int NWG = MT * NXT;         // %8==0 at both call sites
  constexpr int CPX = NWG / 8;
  __shared__ char lds[131072];

  const int bid = blockIdx.x;
  const int wg = (bid & 7) * CPX + (bid >> 3);   // XCD swizzle
  const int bx = NFAST ? (wg % NXT) : (wg / MT);
  const int by = NFAST ? (wg / NXT) : (wg % MT);
  const int m0 = by * 256, n0 = bx * 256;

  const int t = threadIdx.x;
  const int lane = t & 63;
  const int wid = t >> 6;
  const int wr = wid >> 2, wc = wid & 3;     // wave owns C rows wr*128, cols wc*64
  const int laneOff = (lane & 15) * 64 + (lane >> 4) * 16;
  const int swzOff = laneOff ^ (((laneOff >> 9) & 1) << 5) ^ (((laneOff >> 8) & 1) << 4);

  f32x4 acc[8][4] = {};
  f16x8 Aq[4][2], B0q[2][2], B1q[2][2];

#define WRAPT(TT) ((TT) >= NT ? (TT) - NT : (TT))
#define LDA(MH) do { _Pragma("unroll") for (int fm = 0; fm < 4; ++fm) \
    _Pragma("unroll") for (int kk = 0; kk < 2; ++kk) \
      Aq[fm][kk] = *reinterpret_cast<const f16x8*>( \
          bufc + wr * 16384 + ((((MH) * 4 + fm) * 2 + kk)) * 1024 + swzOff); } while (0)
#define LDB(NH, BQ) do { _Pragma("unroll") for (int fn = 0; fn < 2; ++fn) \
    _Pragma("unroll") for (int kk = 0; kk < 2; ++kk) \
      BQ[fn][kk] = *reinterpret_cast<const f16x8*>( \
          bufc + 32768 + (wc >> 1) * 16384 + \
          ((((wc & 1) * 4 + (NH) * 2 + fn) * 2 + kk)) * 1024 + swzOff); } while (0)
#define MFQ(MH, NH, BQ) do { __builtin_amdgcn_s_setprio(1); \
    _Pragma("unroll") for (int fm = 0; fm < 4; ++fm) \
      _Pragma("unroll") for (int fn = 0; fn < 2; ++fn) \
        _Pragma("unroll") for (int kk = 0; kk < 2; ++kk) \
          acc[(MH) * 4 + fm][(NH) * 2 + fn] = __builtin_amdgcn_mfma_f32_16x16x32_f16( \
              Aq[fm][kk], BQ[fn][kk], acc[(MH) * 4 + fm][(NH) * 2 + fn], 0, 0, 0); \
    __builtin_amdgcn_s_setprio(0); } while (0)

  // prologue: T0 complete + T1.B0,B1; vmcnt(4) drains T0, keeps T1.B halves
  stage_half(A, m0,       0,  lds,         wid, lane);   // T0.A0
  stage_half(A, m0 + 128, 0,  lds + 16384, wid, lane);   // T0.A1
  stage_half(B, n0,       0,  lds + 32768, wid, lane);   // T0.B0
  stage_half(B, n0 + 128, 0,  lds + 49152, wid, lane);   // T0.B1
  stage_half(B, n0,       64, lds + 65536 + 32768, wid, lane);  // T1.B0
  stage_half(B, n0 + 128, 64, lds + 65536 + 49152, wid, lane);  // T1.B1
  VM4BAR();

  for (int tau = 0; tau < NT; ++tau) {
    char* bufc = lds + (tau & 1) * 65536;
    char* bufo = lds + ((tau & 1) ^ 1) * 65536;
    // P0: quadrant (0,0); stage (tau+1).A0 -> bufo (readers 1 tile old)
    LDA(0);
    LDB(0, B0q);
    stage_half(A, m0, WRAPT(tau + 1) * 64, bufo, wid, lane);
    MFQ(0, 0, B0q);
    // P1: quadrant (0,1); stage (tau+1).A1 -> bufo
    LDB(1, B1q);
    stage_half(A, m0 + 128, WRAPT(tau + 1) * 64, bufo + 16384, wid, lane);
    MFQ(0, 1, B1q);
    BAR();   // all waves issued their P0/P1 B-reads before B-region restage
    // P2: quadrant (1,1); stage (tau+2).B0 -> bufc (safe post-BAR)
    LDA(1);
    stage_half(B, n0, WRAPT(tau + 2) * 64, bufc + 32768, wid, lane);
    MFQ(1, 1, B1q);
    // P3: stage (tau+2).B1; counted drain; quadrant (1,0) from regs
    stage_half(B, n0 + 128, WRAPT(tau + 2) * 64, bufc + 49152, wid, lane);
    VM4BAR();    // 12 -> 4: drains tile tau+1 fully; keeps (tau+2).B0,B1
    MFQ(1, 0, B0q);
  }

#undef MFQ
#undef LDB
#undef LDA
#undef WRAPT

  // epilogue: C/D layout col = lane&15, row = (lane>>4)*4 + j ; resid fp16
  const float g = EPI ? gam[0] : 0.f;
#pragma unroll
  for (int m = 0; m < 8; ++m)
#pragma unroll
    for (int n = 0; n < 4; ++n)
#pragma unroll
      for (int j = 0; j < 4; ++j) {
        const int r = m0 + wr * 128 + m * 16 + (lane >> 4) * 4 + j;
        const int c = n0 + wc * 64 + n * 16 + (lane & 15);
        const size_t idx = (size_t)r * (size_t)N + (size_t)c;
        float v = acc[m][n][j];
        if (EPI) v = g * v + h2f(resid[idx]);
        C[idx] = v;
      }
}

// ---------------- per-batch: energy -> softmax -> attn out + y = attn@x ----------------
__global__ void __launch_bounds__(256)
attn_fuse(const float* __restrict__ QK,          // [MTOT, 512] cols 0..255=q, 256..511=k
          const unsigned short* __restrict__ xh, // [MTOT, 2048] fp16
          float* __restrict__ attn_out,          // [NB, 36]
          unsigned short* __restrict__ y)        // [MTOT, 2048] fp16
{
  __shared__ float qk[NS * 512];
  __shared__ float eng[36];
  __shared__ float att[36];
  const int b = blockIdx.x;
  const int t = threadIdx.x;
  {
    const f32x4* src = reinterpret_cast<const f32x4*>(QK + (size_t)b * (NS * 512));
    f32x4* dst = reinterpret_cast<f32x4*>(qk);
    for (int i = t; i < (NS * 512) / 4; i += 256) dst[i] = src[i];
  }
  __syncthreads();
  if (t < 144) {
    const int s = t / 24;
    const int rem = t - s * 24;
    const int u = rem >> 2;
    const int sub = rem & 3;
    const float* qr = qk + s * 512;
    const float* kr = qk + u * 512 + 256;
    float sum = 0.f;
    const int d0 = sub * 64;
#pragma unroll 4
    for (int d = 0; d < 64; ++d) sum += qr[d0 + d] * kr[d0 + d];
    sum += __shfl_xor(sum, 1);
    sum += __shfl_xor(sum, 2);
    if (sub == 0) eng[s * 6 + u] = sum;
  }
  __syncthreads();
  if (t < 6) {
    float e[6];
#pragma unroll
    for (int u = 0; u < 6; ++u) e[u] = eng[t * 6 + u];
    float mx = e[0];
#pragma unroll
    for (int u = 1; u < 6; ++u) mx = fmaxf(mx, e[u]);
    float p[6];
    float sm = 0.f;
#pragma unroll
    for (int u = 0; u < 6; ++u) { p[u] = expf(e[u] - mx); sm += p[u]; }
    const float inv = 1.0f / sm;
#pragma unroll
    for (int u = 0; u < 6; ++u) {
      const float a = p[u] * inv;
      att[t * 6 + u] = a;
      attn_out[(size_t)b * 36 + t * 6 + u] = a;
    }
  }
  __syncthreads();
  const unsigned short* xb = xh + (size_t)b * (NS * NC);
  unsigned short* yb = y + (size_t)b * (NS * NC);
  const int c0 = t * 8;
  f32x4 xv[12];
#pragma unroll
  for (int u = 0; u < 6; ++u) {
    u16x8 v = *reinterpret_cast<const u16x8*>(xb + u * NC + c0);
#pragma unroll
    for (int j = 0; j < 4; ++j) {
      xv[2 * u][j] = h2f(v[j]);
      xv[2 * u + 1][j] = h2f(v[4 + j]);
    }
  }
#pragma unroll
  for (int s = 0; s < 6; ++s) {
    f32x4 a0 = 0.f, a1 = 0.f;
#pragma unroll
    for (int u = 0; u < 6; ++u) {
      const float w = att[s * 6 + u];
      a0 += w * xv[2 * u];
      a1 += w * xv[2 * u + 1];
    }
    u16x8 o;
#pragma unroll
    for (int j = 0; j < 4; ++j) { o[j] = f2h_bits(a0[j]); o[4 + j] = f2h_bits(a1[j]); }
    *reinterpret_cast<u16x8*>(yb + s * NC + c0) = o;
  }
}

extern "C" void kernel_launch(void* const* d_in, const int* in_sizes, int n_in,
                              void* d_out, int out_size, void* d_ws, size_t ws_size,
                              hipStream_t stream) {
  (void)in_sizes; (void)n_in; (void)out_size; (void)ws_size;
  const float* x   = (const float*)d_in[0];
  const float* Wq  = (const float*)d_in[1];
  const float* Wk  = (const float*)d_in[2];
  const float* Wv  = (const float*)d_in[3];
  const float* gam = (const float*)d_in[4];
  float* out = (float*)d_out;
  float* attn_out = out + (size_t)MTOT * NC;

  char* ws = (char*)d_ws;
  unsigned short* xh  = (unsigned short*)(ws);                    // 100663296 B
  unsigned short* yb  = (unsigned short*)(ws + 100663296ull);     // 100663296 B (y)
  unsigned short* wqk = (unsigned short*)(ws + 201326592ull);     // 2097152 B
  unsigned short* wvh = (unsigned short*)(ws + 203423744ull);     // 8388608 B
  float*          qkb = (float*)(ws + 211812352ull);              // 50331648 B

  prep_all<<<2048, 256, 0, stream>>>(x, Wq, Wk, Wv, xh, wqk, wvh);

  // QK = x @ [Wq;Wk]^T, single-pass fp16
  gemm256<512, false, false><<<192, 512, 0, stream>>>(
      xh, wqk, qkb, nullptr, nullptr);

  // energies + softmax + attention output + y = attn @ x
  attn_fuse<<<NB, 256, 0, stream>>>(qkb, xh, attn_out, yb);

  // out = gamma * (y @ Wv^T) + x_fp16    (n-fast block order for y L2 reuse)
  gemm256<2048, true, true><<<768, 512, 0, stream>>>(
      yb, wvh, out, xh, gam);
}